// Round 12
// baseline (213.702 us; speedup 1.0000x reference)
//
#include <hip/hip_runtime.h>
#include <hip/hip_bf16.h>
#include <cmath>

#define S_LEN 2048
#define DMODEL 1024
#define NHEADS 16
#define DK 64
#define BATCH 2
#define MTOT (BATCH * S_LEN) /* 4096 */

using short8 = __attribute__((ext_vector_type(8))) short;
using floatx4 = __attribute__((ext_vector_type(4))) float;

// float -> bf16 bits, round-to-nearest-even (scalar path)
__device__ __forceinline__ unsigned short f2b(float f) {
    union { float f; unsigned u; } v; v.f = f;
    unsigned r = v.u + 0x7fff + ((v.u >> 16) & 1);
    return (unsigned short)(r >> 16);
}

// packed 2x float -> bf16x2 (v_cvt_pk_bf16_f32)
__device__ __forceinline__ unsigned pack2(float a, float b) {
    float2 t; t.x = a; t.y = b;
    __hip_bfloat162 h = __float22bfloat162_rn(t);
    union { __hip_bfloat162 h; unsigned u; } v; v.h = h;
    return v.u;
}

// async global->LDS, 16 B/lane. LDS dest is wave-uniform base (+lane*16 by HW).
__device__ __forceinline__ void gload16(const void* g, void* l) {
    __builtin_amdgcn_global_load_lds(
        (const __attribute__((address_space(1))) unsigned int*)g,
        (__attribute__((address_space(3))) unsigned int*)l, 16, 0, 0);
}

#define FENCE() asm volatile("" ::: "memory")

// ---------------------------------------------------------------------------
// Fused preprocessing (single dispatch, blockIdx-range partition):
//   blocks [0, 2048)        : x fp32 -> bf16 cast
//   blocks [2048, 2304)     : RoPE cos/sin tables
//   blocks [2304, 3328)     : W fp32 [k][n] -> bf16 [n][k] transpose
//                             (Wq,Wk head-dims permuted: d -> d/2 or 32+d/2)
// ---------------------------------------------------------------------------
__global__ __launch_bounds__(256) void prep_k(
    const float* __restrict__ x, unsigned short* __restrict__ xb,
    const int* __restrict__ tokpos, float* __restrict__ ct, float* __restrict__ st,
    const float* W0, const float* W1, const float* W2, const float* W3,
    unsigned short* T0, unsigned short* T1, unsigned short* T2, unsigned short* T3) {
    __shared__ float t[64][65];
    const int b = blockIdx.x;
    if (b < 2048) {
        int i = (b * 256 + threadIdx.x) * 8;
        float4 a = *(const float4*)(x + i);
        float4 bb = *(const float4*)(x + i + 4);
        short8 o;
        o[0] = f2b(a.x); o[1] = f2b(a.y); o[2] = f2b(a.z); o[3] = f2b(a.w);
        o[4] = f2b(bb.x); o[5] = f2b(bb.y); o[6] = f2b(bb.z); o[7] = f2b(bb.w);
        *(short8*)(xb + i) = o;
    } else if (b < 2304) {
        int idx = (b - 2048) * 256 + threadIdx.x;  // 0 .. 2048*32-1
        int si = idx >> 5;
        int ip = idx & 31;
        float pos = (float)tokpos[si];
        float inv_freq = powf(10000.0f, -(float)(2 * ip) / 64.0f);
        float ang = pos * inv_freq;
        ct[idx] = cosf(ang);
        st[idx] = sinf(ang);
    } else {
        int id = b - 2304;          // 0..1023
        int z = id >> 8;            // matrix
        int bx = id & 15, by = (id >> 4) & 15;
        const float* W = z == 0 ? W0 : z == 1 ? W1 : z == 2 ? W2 : W3;
        unsigned short* T = z == 0 ? T0 : z == 1 ? T1 : z == 2 ? T2 : T3;
        const bool perm = (z < 2);
        int n0 = bx * 64, k0 = by * 64;
        int rr = threadIdx.x >> 6, cc = threadIdx.x & 63;
#pragma unroll
        for (int r = 0; r < 16; r++) {
            int row = r * 4 + rr;
            t[row][cc] = W[(size_t)(k0 + row) * DMODEL + n0 + cc];
        }
        __syncthreads();
#pragma unroll
        for (int r = 0; r < 16; r++) {
            int row = r * 4 + rr;  // original col within head
            int drow = perm ? (((row & 1) ? 32 : 0) + (row >> 1)) : row;
            T[(size_t)(n0 + drow) * DMODEL + k0 + cc] = f2b(t[cc][row]);
        }
    }
}

// ---------------------------------------------------------------------------
// out += P1 (split-K reduce): 2048 blocks x 256 thr x 8 floats, 48 MB traffic
// ---------------------------------------------------------------------------
__global__ __launch_bounds__(256) void add_k(float* __restrict__ out,
                                             const float* __restrict__ p) {
    int i = (blockIdx.x * 256 + threadIdx.x) * 8;
    float4 a = *(const float4*)(out + i);
    float4 b = *(const float4*)(p + i);
    float4 c = *(const float4*)(out + i + 4);
    float4 d = *(const float4*)(p + i + 4);
    a.x += b.x; a.y += b.y; a.z += b.z; a.w += b.w;
    c.x += d.x; c.y += d.y; c.z += d.z; c.w += d.w;
    *(float4*)(out + i) = a;
    *(float4*)(out + i + 4) = c;
}

// ---------------------------------------------------------------------------
// bf16 MFMA GEMM — R12 rewrite for CO-RESIDENCY (R11 counters: MfmaUtil 14%,
// VALUBusy 8.6%, Occupancy 14% at 192 blocks / 1 block/CU — waves parked at
// barriers with nothing to overlap; V-epilogue blocks were the dispatch tail).
// Now: BM=128, BN=256, BK=32; 8 waves (2M x 4N; per-wave 64x64, acc[4][4]);
// LDS = 10 slots x 8 KB = 80 KB -> 2 blocks/CU (launch_bounds(512,4)).
// Grids: kind0 (32,4,3)=384 blocks (1.5/CU, all CUs busy, V-tail amortized);
// kind1 Wo (32,4,2)=256 blocks split-K=2.
// Rotation: per K-tile 3 halves {A, B0, B1}; stage(t+2) issued during tile t
// (parts 0,1 at phase rh=0; part 2 at rh=1); slot = h%10, reuse distance
// 10 halves = 3.3 tiles (safe: last read of h-10 ends >=2 phases before
// stage of h, all h mod 3). Counted vmcnt(3) per tile boundary (3 ops/tile,
// 1 gload/thread/stage); prologue 6 stages -> vmcnt(3); drain-0 at t==NT-2.
// Per-acc k-accumulation order identical to BK=64 version (ascending 32-k
// steps) -> bit-exact.
// mode 3 (V): direct transposed scatter to Vt (tail now amortized).
// ---------------------------------------------------------------------------
__global__ __launch_bounds__(512, 4) void mm_k(
    const unsigned short* __restrict__ A,
    const unsigned short* __restrict__ Bt0, const unsigned short* __restrict__ Bt1,
    const unsigned short* __restrict__ Bt2,
    void* C0, void* C1, void* C2,
    const float* __restrict__ ct, const float* __restrict__ st, int kind) {
    __shared__ __align__(16) unsigned short blob[10 * 4096];  // 80 KiB

    const int z = blockIdx.z;
    const unsigned short* Bt = (kind == 1) ? Bt0 : (z == 0 ? Bt0 : z == 1 ? Bt1 : Bt2);
    void* C = (kind == 1) ? (z == 0 ? C0 : C1) : (z == 0 ? C0 : z == 1 ? C1 : C2);
    const int mode = (kind == 1) ? 0 : (z == 2 ? 3 : 1);
    const int t0 = (kind == 1) ? z * 16 : 0;   // starting K-tile (BK=32)
    const int NT = (kind == 1) ? 16 : 32;      // K-tiles this block
    // 0.125/ln2: QK^T scaling + exp2-domain softmax, folded into Q
    const float qscale = (z == 0 && kind == 0) ? 0.18033688011112042f : 1.0f;

    const int tid = threadIdx.x;
    const int w = tid >> 6, lane = tid & 63;
    const int l15 = lane & 15, quad = lane >> 4;
    const int wr = w >> 2, wc = w & 3;  // 2M x 4N waves; per-wave out 64x64
    const int m0 = blockIdx.x * 128, n0 = blockIdx.y * 256;

    floatx4 acc[4][4];
#pragma unroll
    for (int i = 0; i < 4; i++)
#pragma unroll
        for (int j = 0; j < 4; j++) acc[i][j] = (floatx4){0.f, 0.f, 0.f, 0.f};

    // stage one 8KB half (tile tt, part: 0=A, 1=B0, 2=B1); 1 gload/thread.
    // group w covers rows w*16+l15, k-cols quad*8..+7 of the 128x32 half.
    auto stage = [&](int tt, int part) {
        const int ts = t0 + tt;
        const int slot = (3 * tt + part) % 10;
        const unsigned short* src =
            (part == 0 ? A + ((size_t)(m0 + w * 16 + l15) << 10)
                       : Bt + ((size_t)(n0 + (part - 1) * 128 + w * 16 + l15) << 10))
            + ts * 32 + quad * 8;
        gload16(src, (char*)blob + slot * 8192 + w * 1024);
    };

    // prologue: tiles 0,1 staged (6 ops); vmcnt(3) -> tile 0 landed,
    // tile 1's 3 halves in flight.
    stage(0, 0); stage(0, 1); stage(0, 2);
    stage(1, 0); stage(1, 1); stage(1, 2);
    asm volatile("s_waitcnt vmcnt(3)" ::: "memory");
    FENCE(); __builtin_amdgcn_s_barrier(); FENCE();

    for (int t = 0; t < NT; ++t) {
        int sA = (3 * t) % 10;
        int sB = sA + 1 + (wc >> 1); if (sB >= 10) sB -= 10;
        const char* LA = (const char*)blob + sA * 8192;
        const char* LB = (const char*)blob + sB * 8192;
#pragma unroll
        for (int rh = 0; rh < 2; ++rh) {
            short8 af[2], bf[4];
#pragma unroll
            for (int ii = 0; ii < 2; ++ii)
                af[ii] = *(const short8*)(LA + (wr * 4 + rh * 2 + ii) * 1024 + lane * 16);
#pragma unroll
            for (int j = 0; j < 4; ++j)
                bf[j] = *(const short8*)(LB + ((wc & 1) * 4 + j) * 1024 + lane * 16);
            if (rh == 0) {
                if (t + 2 < NT) { stage(t + 2, 0); stage(t + 2, 1); }
            } else {
                if (t + 2 < NT) stage(t + 2, 2);
                if (t == NT - 2) asm volatile("s_waitcnt vmcnt(0)" ::: "memory");
                else             asm volatile("s_waitcnt vmcnt(3)" ::: "memory");
            }
            FENCE(); __builtin_amdgcn_s_barrier(); FENCE();
            __builtin_amdgcn_s_setprio(1);
#pragma unroll
            for (int ii = 0; ii < 2; ++ii)
#pragma unroll
                for (int j = 0; j < 4; ++j)
                    acc[rh * 2 + ii][j] =
                        __builtin_amdgcn_mfma_f32_16x16x32_bf16(af[ii], bf[j], acc[rh * 2 + ii][j], 0, 0, 0);
            __builtin_amdgcn_s_setprio(0);
            FENCE(); __builtin_amdgcn_s_barrier(); FENCE();
        }
    }

    // epilogue: C/D layout col = l15, row = quad*4 + reg
#pragma unroll
    for (int i = 0; i < 4; i++) {
        const int rowb = m0 + wr * 64 + i * 16 + quad * 4;
        if (mode == 0) {
            float* Cf = (float*)C;
#pragma unroll
            for (int j = 0; j < 4; j++) {
                int colb = n0 + wc * 64 + j * 16 + l15;
#pragma unroll
                for (int r = 0; r < 4; r++)
                    Cf[(size_t)(rowb + r) * DMODEL + colb] = acc[i][j][r];
            }
        } else if (mode == 1) {
            unsigned short* Cb = (unsigned short*)C;
#pragma unroll
            for (int jh = 0; jh < 2; jh++) {
                int ip = jh * 16 + l15;                   // pair index within head
                int cole = n0 + wc * 64 + jh * 16 + l15;  // even-member column (d'<32)
#pragma unroll
                for (int r = 0; r < 4; r++) {
                    int row = rowb + r;
                    int si = row & (S_LEN - 1);
                    float c = ct[si * 32 + ip] * qscale;
                    float s = st[si * 32 + ip] * qscale;
                    float e = acc[i][jh][r];       // x_even (permuted weights)
                    float od = acc[i][jh + 2][r];  // x_odd (partner col, same thread)
                    Cb[(size_t)row * DMODEL + cole] = f2b(e * c - od * s);
                    Cb[(size_t)row * DMODEL + cole + 32] = f2b(e * s + od * c);
                }
            }
        } else {
            // mode 3: V -> Vt[(bb*1024 + d)][s] direct transposed scatter.
            // acc[i][j][0..3] = 4 s-consecutive values at fixed d -> ushort4.
            unsigned short* Cb = (unsigned short*)C;  // Vt base
            const int bb2 = m0 >> 11;
            const int si = rowb & (S_LEN - 1);
#pragma unroll
            for (int j = 0; j < 4; j++) {
                int colb = n0 + wc * 64 + j * 16 + l15;  // global d
                ushort4 v;
                v.x = f2b(acc[i][j][0]); v.y = f2b(acc[i][j][1]);
                v.z = f2b(acc[i][j][2]); v.w = f2b(acc[i][j][3]);
                *(ushort4*)(Cb + (size_t)(bb2 * 1024 + colb) * S_LEN + si) = v;
            }
        }
    }
}

// ---------------------------------------------------------------------------
// Block-cooperative MFMA flash attention; R4 inner loop VERBATIM, key-loop
// range is a per-block slice [kt0,kt1) for kv-split load shaping. (R8 code,
// measured 52.1 us — best attn config across R1-R9.)
// qt>=10 split into two key-range halves -> slice sizes max 20, 22 slices x
// 32 bh = 704 blocks ~2.75/CU (LDS 50KB -> 3 fit), dispatched descending.
// Split slices write unnormalized fp32 U + per-lane (m,l) partials into the
// dead xb/Wqt/Wkt/Wvt region; mrg_k combines exactly (fp32 reorder only).
// ---------------------------------------------------------------------------
__global__ __launch_bounds__(512) void attn_k(const unsigned short* __restrict__ Q,
                                              const unsigned short* __restrict__ K,
                                              const unsigned short* __restrict__ Vt,
                                              unsigned short* __restrict__ O,
                                              float* __restrict__ Ub,
                                              float* __restrict__ MLb) {
    __shared__ __align__(16) unsigned short Kblob[2][4096];  // 8 KB/buf
    __shared__ __align__(16) unsigned short Vblob[2][4096];
    __shared__ __align__(16) unsigned short Ps[8][16 * 72];  // per-wave P / O-bounce

    // slice tables, descending size {20,18,16,16,16,15,15,14,14,14,13,13,
    // 12,12,12,11,11,10,8,6,4,2}: qt, kt0, kt1, partial-slice idx (-1=direct)
    static const int T_qt[22] = {9, 8, 15, 15, 7, 14, 14, 13, 13, 6, 12,
                                 12, 11, 11, 5, 10, 10, 4, 3, 2, 1, 0};
    static const int T_k0[22] = {0, 0, 0, 16, 0, 0, 15, 0, 14, 0, 0,
                                 13, 0, 12, 0, 0, 11, 0, 0, 0, 0, 0};
    static const int T_k1[22] = {20, 18, 16, 32, 16, 15, 30, 14, 28, 14, 13,
                                 26, 12, 24, 12, 11, 22, 10, 8, 6, 4, 2};
    static const int T_sx[22] = {-1, -1, 10, 11, -1, 8, 9, 6, 7, -1, 4,
                                 5, 2, 3, -1, 0, 1, -1, -1, -1, -1, -1};

    const int tid = threadIdx.x;
    const int w = tid >> 6, lane = tid & 63;
    const int l15 = lane & 15, quad = lane >> 4;
    const int idx = blockIdx.x;      // 704 blocks = 22 slices x 32 bh
    const int sr = idx >> 5;
    const int bh = idx & 31;
    const int bb = bh >> 4, h = bh & 15;
    const int qt = T_qt[sr], kt0 = T_k0[sr], kt1 = T_k1[sr], sx = T_sx[sr];
    const int qbase = qt * 128 + w * 16;
    const int qrow = qbase + l15;

    // Q fragment (B-operand: col=query=l15, k=quad*8), d-halves 0/1
    const size_t qoff = (size_t)(bb * S_LEN + qbase + l15) * DMODEL + h * DK;
    short8 aq0 = *(const short8*)(Q + qoff + quad * 8);
    short8 aq1 = *(const short8*)(Q + qoff + 32 + quad * 8);

    floatx4 o[4];
#pragma unroll
    for (int f = 0; f < 4; f++) o[f] = (floatx4){0.f, 0.f, 0.f, 0.f};
    float mv = -1e30f, lv = 0.f;

    const unsigned short* Kb = K + (size_t)(bb * S_LEN) * DMODEL + h * DK;
    const unsigned short* Vb = Vt + (size_t)(bb * 1024 + h * DK) * S_LEN;
    unsigned short* ps = &Ps[w][0];

    // stage 64-key K/V tile into blob buffer b (2 gload16/thread, 8 waves)
    auto stage = [&](int b, int kb) {
#pragma unroll
        for (int it = 0; it < 2; it++) {
            int g = it * 8 + w;  // wave-uniform 0..15; 0..7 K-groups, 8..15 V-groups
            if (g < 8) {
                const unsigned short* gp =
                    Kb + (size_t)(kb + (g >> 1) * 16 + l15) * DMODEL + (g & 1) * 32 + quad * 8;
                gload16(gp, (char*)&Kblob[b][0] + g * 1024);
            } else {
                int gv = g - 8;
                const unsigned short* gp =
                    Vb + (size_t)((gv >> 1) * 16 + l15) * S_LEN + kb + (gv & 1) * 32 + quad * 8;
                gload16(gp, (char*)&Vblob[b][0] + gv * 1024);
            }
        }
    };

    stage(0, kt0 * 64);
    for (int kt = kt0; kt < kt1; kt++) {
        const int b = (kt - kt0) & 1;
        const int kb = kt * 64;
        __syncthreads();  // staging of buf b complete; buf b^1 reads done
        if (kt + 1 < kt1) stage(b ^ 1, (kt + 1) * 64);

        // waves skip tiles fully above their causal row range: exact zeros.
        if (kb <= qbase + 15) {
            // QK^T: S^T[key 64][q 16]
            const unsigned short* kbb = &Kblob[b][0];
            floatx4 c[4];
            __builtin_amdgcn_s_setprio(1);
#pragma unroll
            for (int g = 0; g < 4; g++) {
                short8 kf0 = *(const short8*)(kbb + (g * 2 + 0) * 512 + lane * 8);
                short8 kf1 = *(const short8*)(kbb + (g * 2 + 1) * 512 + lane * 8);
                floatx4 t = {0.f, 0.f, 0.f, 0.f};
                t = __builtin_amdgcn_mfma_f32_16x16x32_bf16(kf0, aq0, t, 0, 0, 0);
                c[g] = __builtin_amdgcn_mfma_f32_16x16x32_bf16(kf1, aq1, t, 0, 0, 0);
            }
            __builtin_amdgcn_s_setprio(0);

            // softmax over 16 keys/lane (exp2 domain; scores pre-scaled via Q)
            float sv[16];
            if (kb + 63 <= qbase) {  // wave-uniform: whole tile causal-valid
#pragma unroll
                for (int g = 0; g < 4; g++)
#pragma unroll
                    for (int r = 0; r < 4; r++) sv[g * 4 + r] = c[g][r];
            } else {
#pragma unroll
                for (int g = 0; g < 4; g++)
#pragma unroll
                    for (int r = 0; r < 4; r++) {
                        int key = kb + g * 16 + quad * 4 + r;
                        sv[g * 4 + r] = (key <= qrow) ? c[g][r] : -1e30f;
                    }
            }
            // tree max (v_max3-friendly, depth 4; fmax exact)
            float t0 = fmaxf(fmaxf(sv[0], sv[1]), sv[2]);
            float t1 = fmaxf(fmaxf(sv[3], sv[4]), sv[5]);
            float t2 = fmaxf(fmaxf(sv[6], sv[7]), sv[8]);
            float t3 = fmaxf(fmaxf(sv[9], sv[10]), sv[11]);
            float t4 = fmaxf(fmaxf(sv[12], sv[13]), sv[14]);
            float mx = fmaxf(fmaxf(fmaxf(t0, t1), fmaxf(t2, t3)), fmaxf(t4, sv[15]));
            mx = fmaxf(mx, __shfl_xor(mx, 16));
            mx = fmaxf(mx, __shfl_xor(mx, 32));

            // wave-uniform rescale skip: alpha==1 exactly when no growth
            if (!__all(mx <= mv)) {
                float mnew = fmaxf(mv, mx);
                float alpha = exp2f(mv - mnew);
                mv = mnew;
                lv *= alpha;
#pragma unroll
                for (int f = 0; f < 4; f++) {
                    o[f][0] *= alpha; o[f][1] *= alpha;
                    o[f][2] *= alpha; o[f][3] *= alpha;
                }
            }
            float p[16], psum = 0.f;
#pragma unroll
            for (int i = 0; i < 16; i++) {
                p[i] = exp2f(sv[i] - mv);
                psum += p[i];
            }
            lv += psum;  // per-lane partial; cross-quad reduce at end / in merge

            // P -> LDS (row=q l15, key = g*16+quad*4..+3), stride 72 shorts
#pragma unroll
            for (int g = 0; g < 4; g++) {
                uint2 pk;
                pk.x = pack2(p[g * 4 + 0], p[g * 4 + 1]);
                pk.y = pack2(p[g * 4 + 2], p[g * 4 + 3]);
                *(uint2*)(ps + l15 * 72 + g * 16 + quad * 4) = pk;
            }
            // P^T B-frags (col=q l15, keys quad*8 / +32)
            short8 pf0 = *(const short8*)(ps + l15 * 72 + quad * 8);
            short8 pf1 = *(const short8*)(ps + l15 * 72 + 32 + quad * 8);
            const unsigned short* vbb = &Vblob[b][0];
            __builtin_amdgcn_s_setprio(1);
#pragma unroll
            for (int f = 0; f < 4; f++) {
                short8 vf0 = *(const short8*)(vbb + (f * 2 + 0) * 512 + lane * 8);
                short8 vf1 = *(const short8*)(vbb + (f * 2 + 1) * 512 + lane * 8);
                o[f] = __builtin_amdgcn_mfma_f32_16x16x32_bf16(vf0, pf0, o[f], 0, 0, 0);
                o[f] = __builtin_amdgcn_mfma_f32_16x16x32_bf16(vf1, pf1, o[f], 0, 0, 0);
            }
            __builtin_amdgcn_s_setprio(0);
        }
    }

    if (sx >= 0) {
        // split slice: dump unnormalized fp32 U (fragment layout) + per-lane
        // m, l. No quad reduce, no normalize — mrg_k does the exact combine.
        const int slot = sx * 32 + bh;
        float* up = Ub + (size_t)slot * 8192 + tid * 16;
#pragma unroll
        for (int f = 0; f < 4; f++) {
            float4 v; v.x = o[f][0]; v.y = o[f][1]; v.z = o[f][2]; v.w = o[f][3];
            *(float4*)(up + f * 4) = v;
        }
        float* mlp = MLb + (size_t)slot * 1024 + tid * 2;
        mlp[0] = mv;
        mlp[1] = lv;
    } else {
        // direct store: final l reduction across quads, un-transpose via LDS
        lv += __shfl_xor(lv, 16);
        lv += __shfl_xor(lv, 32);
        float inv = 1.0f / lv;
        __syncthreads();  // safe reuse of Ps region
#pragma unroll
        for (int f = 0; f < 4; f++) {
            uint2 pk;
            pk.x = pack2(o[f][0] * inv, o[f][1] * inv);
            pk.y = pack2(o[f][2] * inv, o[f][3] * inv);
            *(uint2*)(ps + l15 * 72 + f * 16 + quad * 4) = pk;  // row=q, d=f*16+quad*4
        }
        short8 r0 = *(const short8*)(ps + l15 * 72 + quad * 8);
        short8 r1 = *(const short8*)(ps + l15 * 72 + 32 + quad * 8);
        size_t obase = (size_t)(bb * S_LEN + qbase + l15) * DMODEL + h * DK;
        *(short8*)(O + obase + quad * 8) = r0;
        *(short8*)(O + obase + 32 + quad * 8) = r1;
    }
}

// ---------------------------------------------------------------------------
// Merge the two kv-split halves of qt>=10: exact online-softmax combine.
// Grid 192 = 6 qt x 32 bh, 256 thr: thread owns (q = tid>>1, d-half tid&1).
// U layout (from attn dump): off(q,d) = ((q>>4)*64 + ((d>>2)&3)*16 + (q&15))
//   *16 + (d>>4)*4 + (d&3).  m per (q): tid quad=0; l = sum over 4 quads.
// ---------------------------------------------------------------------------
__global__ __launch_bounds__(256) void mrg_k(const float* __restrict__ Ub,
                                             const float* __restrict__ MLb,
                                             unsigned short* __restrict__ O) {
    const int pid = blockIdx.x;
    const int qt = 10 + (pid >> 5);
    const int bh = pid & 31;
    const int bb = bh >> 4, h = bh & 15;
    const int slotA = ((qt - 10) * 2) * 32 + bh;
    const int slotB = slotA + 32;
    const int tid = threadIdx.x;
    const int q = tid >> 1, dh = tid & 1;
    const int tq = (q >> 4) * 64 + (q & 15);

    const float* mlA = MLb + (size_t)slotA * 1024;
    const float* mlB = MLb + (size_t)slotB * 1024;
    float mA = mlA[tq * 2], mB = mlB[tq * 2];
    float lA = 0.f, lB = 0.f;
#pragma unroll
    for (int qd = 0; qd < 4; qd++) {
        lA += mlA[(tq + qd * 16) * 2 + 1];
        lB += mlB[(tq + qd * 16) * 2 + 1];
    }
    float m = fmaxf(mA, mB);
    float wA = exp2f(mA - m), wB = exp2f(mB - m);
    float inv = 1.0f / (lA * wA + lB * wB);

    const float* uA = Ub + (size_t)slotA * 8192;
    const float* uB = Ub + (size_t)slotB * 8192;
    unsigned short ov[32];
#pragma unroll
    for (int dd = 0; dd < 32; dd++) {
        int d = dh * 32 + dd;
        int uoff = ((q >> 4) * 64 + ((d >> 2) & 3) * 16 + (q & 15)) * 16 + (d >> 4) * 4 + (d & 3);
        float v = (uA[uoff] * wA + uB[uoff] * wB) * inv;
        ov[dd] = f2b(v);
    }
    size_t obase = (size_t)(bb * S_LEN + qt * 128 + q) * DMODEL + h * DK + dh * 32;
#pragma unroll
    for (int c = 0; c < 4; c++)
        *(short8*)(O + obase + c * 8) = *(short8*)&ov[c * 8];
}

// ---------------------------------------------------------------------------
extern "C" void kernel_launch(void* const* d_in, const int* in_sizes, int n_in,
                              void* d_out, int out_size, void* d_ws,
                              size_t ws_size, hipStream_t stream) {
    const float* x = (const float*)d_in[0];
    const float* Wq = (const float*)d_in[1];
    const float* Wk = (const float*)d_in[2];
    const float* Wv = (const float*)d_in[3];
    const float* Wo = (const float*)d_in[4];
    const int* tokpos = (const int*)d_in[5];
    float* out = (float*)d_out;

    const size_t MD = (size_t)MTOT * DMODEL;  // 4194304
    const size_t WD = (size_t)DMODEL * DMODEL;
    unsigned short* xb = (unsigned short*)d_ws;
    unsigned short* Wqt = xb + MD;
    unsigned short* Wkt = Wqt + WD;
    unsigned short* Wvt = Wkt + WD;
    unsigned short* Wot = Wvt + WD;
    unsigned short* Q = Wot + WD;
    unsigned short* K = Q + MD;
    unsigned short* V = K + MD;   // scratch; used as attention output O
    unsigned short* Vt = V + MD;  // [b*1024 + d][s] — written directly by mm_k
    float* ct = (float*)(Vt + MD);
    float* st = ct + S_LEN * 32;
    unsigned short* O = V;
    // split-K partial for Wo: 16 MB fp32 over the dead Q+K regions.
    float* P1 = (float*)Q;
    // attn kv-split partials: 14.2 MB over dead xb+Wqt+Wkt+Wvt (dead after
    // QKV mm; Wo mm reads only O (=V region) and Wot).
    float* Ub = (float*)xb;                 // 384 slots x 8192 floats (12.6 MB)
    float* MLb = Ub + (size_t)384 * 8192;   // 384 slots x 1024 floats (1.6 MB)

    // fused preprocessing: cast + rope tables + weight transposes
    prep_k<<<dim3(3328), dim3(256), 0, stream>>>(x, xb, tokpos, ct, st,
                                                 Wq, Wk, Wv, Wo, Wqt, Wkt, Wvt, Wot);

    // Q (RoPE * 0.125/ln2), K (RoPE), V -> Vt transposed-scatter;
    // 128x256 tiles, 384 blocks, 2 blocks/CU co-resident
    mm_k<<<dim3(32, 4, 3), dim3(512), 0, stream>>>(xb, Wqt, Wkt, Wvt,
                                                   (void*)Q, (void*)K, (void*)Vt, ct, st, 0);
    // kv-split flash attention (704 uniform-ish slices) + exact merge
    attn_k<<<dim3(704), dim3(512), 0, stream>>>(Q, K, Vt, O, Ub, MLb);
    mrg_k<<<dim3(192), dim3(256), 0, stream>>>(Ub, MLb, O);
    // output projection: split-K=2, 256 blocks full chip, fp32 stores, reduce
    mm_k<<<dim3(32, 4, 2), dim3(512), 0, stream>>>(O, Wot, Wot, Wot,
                                                   (void*)out, (void*)P1, (void*)P1, ct, st, 1);
    add_k<<<dim3(2048), dim3(256), 0, stream>>>(out, P1);
}